// Round 6
// baseline (89.891 us; speedup 1.0000x reference)
//
#include <hip/hip_runtime.h>
#include <math.h>

#define P65 65

// ---- Parity-split operator tables (device-built each launch; deterministic) ----
__device__ float g_Rc[4*33*9];   // [w][i<33][m<9] : cos(2*pi*i*r/65), i==0 -> 1 ; rows r=w+4m (<=32)
__device__ float g_Rs[4*32*8];   // [w][i<32][m<8] : sin(2*pi*(i+1)*mf/65)      ; rows mf=w+4m+1
__device__ float g_G [65*33];    // full parity table for col-64 tails
__device__ float g_Mp[65*65];    // spectral multiplier (norms folded); [0][0]=0

__device__ __constant__ float c_DOMAIN[8] = {0.75f,1.0f,0.75f,1.0f,0.75f,1.0f,0.75f,1.0f};

__device__ inline double ctab(int a, int b) {           // cos(2*pi*a*b/65)
  int prod = (a*b) % 65;
  return cos(6.283185307179586476925286766559 * (double)prod / 65.0);
}
__device__ inline double stab(int a, int b) {           // sin(2*pi*a*b/65)
  int prod = (a*b) % 65;
  return sin(6.283185307179586476925286766559 * (double)prod / 65.0);
}

__global__ void init_tables() {
  int tid = blockIdx.x*blockDim.x + threadIdx.x;
  int nth = gridDim.x*blockDim.x;
  for (int idx = tid; idx < 4*33*9; idx += nth) {
    int w = idx/(33*9), rem = idx%(33*9), i = rem/9, m = rem%9;
    int r = w + 4*m;
    g_Rc[idx] = (r <= 32) ? (float)((i==0) ? 1.0 : ctab(i, r)) : 0.f;
  }
  for (int idx = tid; idx < 4*32*8; idx += nth) {
    int w = idx/(32*8), rem = idx%(32*8), i = rem/8, m = rem%8;
    int mf = w + 4*m + 1;
    g_Rs[idx] = (float)stab(i+1, mf);
  }
  for (int idx = tid; idx < 65*33; idx += nth) {
    int r = idx/33, i = idx%33;
    float v;
    if (r <= 32) v = (i==0) ? 1.f : (float)ctab(i, r);
    else         v = (i==0) ? 0.f : (float)stab(i, r-32);
    g_G[idx] = v;
  }
  for (int idx = tid; idx < 65*65; idx += nth) {
    int k1 = idx/65, k2 = idx%65;
    float v = 0.f;
    if (k1 | k2) {
      double n1 = (k1==0)?(1.0/65.0):(2.0/65.0);
      double n2 = (k2==0)?(1.0/65.0):(2.0/65.0);
      int m1 = (k1<=32)?k1:(k1-32), m2 = (k2<=32)?k2:(k2-32);
      double b1 = 6.283185307179586476925286766559*(double)m1/65.0;
      double b2 = 6.283185307179586476925286766559*(double)m2/65.0;
      v = (float)(-(n1*n2)/(b1*b1 + b2*b2));
    }
    g_Mp[idx] = v;
  }
}

__device__ inline float bperm_f(int addr4, float v) {
  return __int_as_float(__builtin_amdgcn_ds_bpermute(addr4, __float_as_int(v)));
}
__device__ inline float shflx(float v, int srclane) { return __shfl(v, srclane, 64); }

// Column combine map (synthesis half-merge along a row): out[c] = X[m1] + sg*X[m2]
__device__ inline void colmap(int c, int& m1, int& m2, float& sg) {
  m1 = (c<=32) ? c : (65-c);
  m2 = (c==0) ? 0 : ((c<=32) ? (32+c) : (97-c));
  sg = (c==0) ? 0.f : ((c<=32) ? 1.f : -1.f);
}
__device__ inline float psiv(const float* __restrict__ A_, int j, int m1, int m2, float sg) {
  return fmaf(sg, A_[j*P65+m2], A_[j*P65+m1]);
}

// ---- S1: EO1 fused into reads (row fold), EO2 fused into writes (lane fold via bpermute) ----
template<int MPW, bool SIN>
__device__ inline void s1_fused(const float* __restrict__ tw,
                                const float* __restrict__ A0_, const float* __restrict__ A1_,
                                float* __restrict__ B0_, float* __restrict__ B1_,
                                int w4, int lane)
{
  float a0[MPW], a1[MPW];
  #pragma unroll
  for (int m=0;m<MPW;++m){ a0[m]=0.f; a1[m]=0.f; }
  #pragma unroll 4
  for (int i = (SIN?1:0); i<=32; ++i) {
    float u0 = A0_[i*P65+lane], u1 = A1_[i*P65+lane];
    float v0, v1;
    if (i==0) { v0=u0; v1=u1; }
    else {
      int p = (i==1)?0:(65-i);
      float q0 = A0_[p*P65+lane], q1 = A1_[p*P65+lane];
      v0 = SIN ? (u0-q0) : (u0+q0);
      v1 = SIN ? (u1-q1) : (u1+q1);
    }
    const float* ti = tw + (SIN ? (i-1) : i)*MPW;
    #pragma unroll
    for (int m=0;m<MPW;++m){ float tv=ti[m]; a0[m]=fmaf(tv,v0,a0[m]); a1[m]=fmaf(tv,v1,a1[m]); }
  }
  // EO2 lane-fold: lane c2 pairs with lane (c2==1 ? 0 : 65-c2)
  int partner = (lane==1) ? 0 : ((65-lane) & 63);
  int pa4 = partner*4;
  bool lo = (lane>=1 && lane<=32);
  #pragma unroll
  for (int m=0;m<MPW;++m) {
    int r = SIN ? (33+w4+4*m) : (w4+4*m);
    if (!SIN && r>32) continue;
    float p0 = bperm_f(pa4, a0[m]);
    float p1 = bperm_f(pa4, a1[m]);
    if (lane==0) { B0_[r] = a0[m]; B1_[r] = a1[m]; }
    if (lo) {
      B0_[lane*P65+r]      = a0[m]+p0;
      B0_[(lane+32)*P65+r] = a0[m]-p0;
      B1_[lane*P65+r]      = a1[m]+p1;
      B1_[(lane+32)*P65+r] = a1[m]-p1;
    }
  }
}

// ---- S2/S3 core (unchanged from R5): contract folded/freq rows, transposed write ----
template<int K, int MPW, bool SIN, bool SCALE>
__device__ inline void mm_half2(const float* __restrict__ tw,
                                const float* __restrict__ L0,
                                const float* __restrict__ L1,
                                float* __restrict__ O0,
                                float* __restrict__ O1,
                                int w4, int lane)
{
  float a0[MPW], a1[MPW];
  #pragma unroll
  for (int m=0;m<MPW;++m) { a0[m]=0.f; a1[m]=0.f; }
  const int inBase = SIN ? 33 : 0;
  #pragma unroll 4
  for (int i=0;i<K;++i) {
    float lv0 = L0[(inBase+i)*P65 + lane];
    float lv1 = L1[(inBase+i)*P65 + lane];
    const float* ti = tw + i*MPW;
    #pragma unroll
    for (int m=0;m<MPW;++m) {
      float tv = ti[m];
      a0[m] = fmaf(tv, lv0, a0[m]);
      a1[m] = fmaf(tv, lv1, a1[m]);
    }
  }
  #pragma unroll
  for (int m=0;m<MPW;++m) {
    int r = SIN ? (33 + w4 + 4*m) : (w4 + 4*m);
    if (SIN || r <= 32) {
      float v0 = a0[m], v1 = a1[m];
      if (SCALE) { float mp = g_Mp[r*P65 + lane]; v0 *= mp; v1 *= mp; }
      O0[lane*P65 + r] = v0;
      O1[lane*P65 + r] = v1;
    }
  }
}

template<bool SCALE>
__device__ inline void mm_stage2(const float* __restrict__ L0, const float* __restrict__ L1,
                                 float* __restrict__ O0, float* __restrict__ O1,
                                 int wvu, int lane)
{
  if (wvu < 4) mm_half2<33,9,false,SCALE>(g_Rc + wvu*(33*9), L0, L1, O0, O1, wvu, lane);
  else         mm_half2<32,8,true ,SCALE>(g_Rs + (wvu-4)*(32*8), L0, L1, O0, O1, wvu-4, lane);
}

// ---- S4 with combine3 fused into reads ----
template<int K, int MPW, bool SIN>
__device__ inline void s4_fused(const float* __restrict__ tw,
                                const float* __restrict__ B0_, const float* __restrict__ B1_,
                                float* __restrict__ A0_, float* __restrict__ A1_,
                                int w4, int lane)
{
  float a0[MPW], a1[MPW];
  #pragma unroll
  for (int m=0;m<MPW;++m){ a0[m]=0.f; a1[m]=0.f; }
  int m1, m2; float sg;
  colmap(lane, m1, m2, sg);
  const int base = SIN ? 33 : 0;
  #pragma unroll 4
  for (int i=0;i<K;++i) {
    int row = base + i;
    float u0 = fmaf(sg, B0_[row*P65+m2], B0_[row*P65+m1]);
    float u1 = fmaf(sg, B1_[row*P65+m2], B1_[row*P65+m1]);
    const float* ti = tw + i*MPW;
    #pragma unroll
    for (int m=0;m<MPW;++m){ float tv=ti[m]; a0[m]=fmaf(tv,u0,a0[m]); a1[m]=fmaf(tv,u1,a1[m]); }
  }
  #pragma unroll
  for (int m=0;m<MPW;++m) {
    int r = SIN ? (33+w4+4*m) : (w4+4*m);
    if (!SIN && r>32) continue;
    A0_[lane*P65+r] = a0[m];
    A1_[lane*P65+r] = a1[m];
  }
}

// ---- stencil with combine4 fused into psi reads; x from regs/shuffles/stash ----
__device__ inline void stencil_img(const float* __restrict__ A_,
                                   const float* __restrict__ St,
                                   const float* __restrict__ xr,
                                   float mu, float id2,
                                   float* __restrict__ op,
                                   int wvu, int lane, bool store)
{
  const int c = lane, cm = (c+63)&63, cp = (c+1)&63;
  const int lm = (lane+63)&63, lp = (lane+1)&63;
  int q1c,q2c,q1m,q2m,q1p,q2p; float qsc,qsm,qsp;
  colmap(c ,q1c,q2c,qsc);
  colmap(cm,q1m,q2m,qsm);
  colmap(cp,q1p,q2p,qsp);
  const int j0  = wvu*8;
  const int jm0 = (j0+63)&63;
  const int sA  = 2*((wvu+7)&7)+1;   // x row j0-1
  const int sB  = 2*((wvu+1)&7);     // x row j0+8

  float xm_m = St[sA*P65+cm], xm_c = St[sA*P65+c], xm_p = St[sA*P65+cp];
  float xc_c = xr[0];
  float xc_m = shflx(xc_c, lm), xc_p = shflx(xc_c, lp);
  float pm_m = psiv(A_,jm0,q1m,q2m,qsm), pm_c = psiv(A_,jm0,q1c,q2c,qsc), pm_p = psiv(A_,jm0,q1p,q2p,qsp);
  float pc_m = psiv(A_,j0 ,q1m,q2m,qsm), pc_c = psiv(A_,j0 ,q1c,q2c,qsc), pc_p = psiv(A_,j0 ,q1p,q2p,qsp);

  #pragma unroll
  for (int m=0;m<8;++m) {
    int j = j0 + m, jp = (j+1)&63;
    float xn_c, xn_m, xn_p;
    if (m < 7) { xn_c = xr[m+1]; xn_m = shflx(xn_c, lm); xn_p = shflx(xn_c, lp); }
    else       { xn_m = St[sB*P65+cm]; xn_c = St[sB*P65+c]; xn_p = St[sB*P65+cp]; }
    float pn_m = psiv(A_,jp,q1m,q2m,qsm), pn_c = psiv(A_,jp,q1c,q2c,qsc), pn_p = psiv(A_,jp,q1p,q2p,qsp);

    float J1 = (pn_c - pm_c)*(xc_p - xc_m) - (pc_p - pc_m)*(xn_c - xm_c);
    float J2 = xc_p*(pn_p - pm_p) - xc_m*(pn_m - pm_m)
             - xn_c*(pn_p - pn_m) + xm_c*(pm_p - pm_m);
    float J3 = xn_p*(pn_c - pc_p) - xm_m*(pc_m - pm_c)
             - xn_m*(pn_c - pc_m) + xm_p*(pc_p - pm_c);
    float lap = (xm_c + xn_c + xc_m + xc_p + xn_m - 4.0f*xc_c) * id2;

    if (store) op[j*64 + c] = -(J1 + J2 + J3)*(0.25f/3.0f) + mu*lap;

    xm_m=xc_m; xm_c=xc_c; xm_p=xc_p;  pm_m=pc_m; pm_c=pc_c; pm_p=pc_p;
    xc_m=xn_m; xc_c=xn_c; xc_p=xn_p;  pc_m=pn_m; pc_c=pn_c; pc_p=pn_p;
  }
}

__global__ void __launch_bounds__(512) pde_main(const float* __restrict__ y0,
                                                const int*   __restrict__ env,
                                                const float* __restrict__ params,
                                                float*       __restrict__ out,
                                                int B)
{
  __shared__ float A0[P65*P65];
  __shared__ float B0[P65*P65];
  __shared__ float A1[P65*P65];
  __shared__ float B1[P65*P65];
  __shared__ float S0x[16*P65];   // x boundary rows (rows 8w and 8w+7), image 0
  __shared__ float S1x[16*P65];   // image 1

  const int t    = threadIdx.x;
  const int lane = t & 63;
  const int wvu  = __builtin_amdgcn_readfirstlane(t >> 6);

  const int b0  = 2*blockIdx.x;
  const int b1r = 2*blockIdx.x + 1;
  const bool has2 = (b1r < B);
  const int b1 = has2 ? b1r : b0;

  const int   e0 = env[b0], e1 = env[b1];
  const float mu0 = params[2*e0], mu1 = params[2*e1];
  const float fdx0 = c_DOMAIN[e0] * (float)(3.14159265358979323846/64.0);
  const float fdx1 = c_DOMAIN[e1] * (float)(3.14159265358979323846/64.0);
  const float idx2_0 = 1.0f/(fdx0*fdx0);
  const float idx2_1 = 1.0f/(fdx1*fdx1);

  // ---- Phase L: load 8 contiguous rows per wave; W=-x -> A; stash boundary x rows ----
  const float* xb0 = y0 + (size_t)b0*4096;
  const float* xb1 = y0 + (size_t)b1*4096;
  float xr0[8], xr1[8];
  #pragma unroll
  for (int k=0;k<8;++k) {
    int j = 8*wvu + k;
    xr0[k] = xb0[j*64 + lane];
    xr1[k] = xb1[j*64 + lane];
    A0[j*P65 + lane] = -xr0[k];
    A1[j*P65 + lane] = -xr1[k];
  }
  S0x[(2*wvu  )*P65 + lane] = xr0[0];
  S0x[(2*wvu+1)*P65 + lane] = xr0[7];
  S1x[(2*wvu  )*P65 + lane] = xr1[0];
  S1x[(2*wvu+1)*P65 + lane] = xr1[7];
  __syncthreads();

  // ---- Phase S1: dim-1 analysis, EO1-fused reads, EO2-fused bpermute writes : A -> B ----
  if (wvu < 4) s1_fused<9,false>(g_Rc + wvu*(33*9), A0, A1, B0, B1, wvu, lane);
  else         s1_fused<8,true >(g_Rs + (wvu-4)*(32*8), A0, A1, B0, B1, wvu-4, lane);
  __syncthreads();

  // ---- Phase S2: dim-2 analysis x Mp : B -> A ; tail computes row k1=64 ----
  mm_stage2<true>(B0, B1, A0, A1, wvu, lane);
  if (t < 65) {
    float acc0 = 0.f, acc1 = 0.f;
    if (t <= 32) {
      for (int i=0;i<33;++i) { float g = g_G[t*33+i]; acc0 = fmaf(g, B0[i*P65+64], acc0); acc1 = fmaf(g, B1[i*P65+64], acc1); }
    } else {
      for (int i=1;i<33;++i) { float g = g_G[t*33+i]; acc0 = fmaf(g, B0[(32+i)*P65+64], acc0); acc1 = fmaf(g, B1[(32+i)*P65+64], acc1); }
    }
    float mp = g_Mp[64*P65 + t];
    A0[64*P65 + t] = acc0 * mp;
    A1[64*P65 + t] = acc1 * mp;
  }
  __syncthreads();

  // ---- Phase S3: dim-1 synthesis halves : A -> B ; tail computes row 64 ----
  mm_stage2<false>(A0, A1, B0, B1, wvu, lane);
  if (t < 65) {
    float acc0 = 0.f, acc1 = 0.f;
    if (t <= 32) {
      for (int i=0;i<33;++i) { float g = g_G[t*33+i]; acc0 = fmaf(g, A0[i*P65+64], acc0); acc1 = fmaf(g, A1[i*P65+64], acc1); }
    } else {
      for (int i=1;i<33;++i) { float g = g_G[t*33+i]; acc0 = fmaf(g, A0[(32+i)*P65+64], acc0); acc1 = fmaf(g, A1[(32+i)*P65+64], acc1); }
    }
    B0[64*P65 + t] = acc0;
    B1[64*P65 + t] = acc1;
  }
  __syncthreads();

  // ---- Phase S4: dim-2 synthesis halves, combine3-fused reads : B -> A ----
  if (wvu < 4) s4_fused<33,9,false>(g_Rc + wvu*(33*9), B0, B1, A0, A1, wvu, lane);
  else         s4_fused<32,8,true >(g_Rs + (wvu-4)*(32*8), B0, B1, A0, A1, wvu-4, lane);
  __syncthreads();

  // ---- Phase ST: stencil; psi via combine4-fused reads; x from regs/shuffles/stash ----
  stencil_img(A0, S0x, xr0, mu0, idx2_0, out + (size_t)b0*4096, wvu, lane, true);
  stencil_img(A1, S1x, xr1, mu1, idx2_1, out + (size_t)b1*4096, wvu, lane, has2);
}

extern "C" void kernel_launch(void* const* d_in, const int* in_sizes, int n_in,
                              void* d_out, int out_size, void* d_ws, size_t ws_size,
                              hipStream_t stream) {
  const float* y0     = (const float*)d_in[1];
  const int*   env    = (const int*)  d_in[2];
  const float* params = (const float*)d_in[3];
  float*       out    = (float*)d_out;
  int B = in_sizes[1] / 4096;
  int nb = (B + 1) / 2;

  init_tables<<<96, 256, 0, stream>>>();
  pde_main<<<nb, 512, 0, stream>>>(y0, env, params, out, B);
}

// Round 7
// 71.326 us; speedup vs baseline: 1.2603x; 1.2603x over previous
//
#include <hip/hip_runtime.h>
#include <math.h>

#define P65 65

// ---- Parity-split operator tables (device-built each launch; deterministic) ----
__device__ float g_Rc[4*33*9];   // [w][i<33][m<9] : cos(2*pi*i*r/65), i==0 -> 1 ; rows r=w+4m (<=32)
__device__ float g_Rs[4*32*8];   // [w][i<32][m<8] : sin(2*pi*(i+1)*mf/65)      ; rows mf=w+4m+1
__device__ float g_G [65*33];    // full parity table for col-64 tails
__device__ float g_Mp[65*65];    // spectral multiplier (norms folded); [0][0]=0

__device__ __constant__ float c_DOMAIN[8] = {0.75f,1.0f,0.75f,1.0f,0.75f,1.0f,0.75f,1.0f};

__device__ inline double ctab(int a, int b) {           // cos(2*pi*a*b/65)
  int prod = (a*b) % 65;
  return cos(6.283185307179586476925286766559 * (double)prod / 65.0);
}
__device__ inline double stab(int a, int b) {           // sin(2*pi*a*b/65)
  int prod = (a*b) % 65;
  return sin(6.283185307179586476925286766559 * (double)prod / 65.0);
}

__global__ void init_tables() {
  int tid = blockIdx.x*blockDim.x + threadIdx.x;
  int nth = gridDim.x*blockDim.x;
  for (int idx = tid; idx < 4*33*9; idx += nth) {
    int w = idx/(33*9), rem = idx%(33*9), i = rem/9, m = rem%9;
    int r = w + 4*m;
    g_Rc[idx] = (r <= 32) ? (float)((i==0) ? 1.0 : ctab(i, r)) : 0.f;
  }
  for (int idx = tid; idx < 4*32*8; idx += nth) {
    int w = idx/(32*8), rem = idx%(32*8), i = rem/8, m = rem%8;
    int mf = w + 4*m + 1;
    g_Rs[idx] = (float)stab(i+1, mf);
  }
  for (int idx = tid; idx < 65*33; idx += nth) {
    int r = idx/33, i = idx%33;
    float v;
    if (r <= 32) v = (i==0) ? 1.f : (float)ctab(i, r);
    else         v = (i==0) ? 0.f : (float)stab(i, r-32);
    g_G[idx] = v;
  }
  for (int idx = tid; idx < 65*65; idx += nth) {
    int k1 = idx/65, k2 = idx%65;
    float v = 0.f;
    if (k1 | k2) {
      double n1 = (k1==0)?(1.0/65.0):(2.0/65.0);
      double n2 = (k2==0)?(1.0/65.0):(2.0/65.0);
      int m1 = (k1<=32)?k1:(k1-32), m2 = (k2<=32)?k2:(k2-32);
      double b1 = 6.283185307179586476925286766559*(double)m1/65.0;
      double b2 = 6.283185307179586476925286766559*(double)m2/65.0;
      v = (float)(-(n1*n2)/(b1*b1 + b2*b2));
    }
    g_Mp[idx] = v;
  }
}

__device__ inline float shflx(float v, int srclane) { return __shfl(v, srclane, 64); }

// Dual-image half-matmul: contracts over rows of L0/L1, transposed write to O0/O1.
template<int K, int MPW, bool SIN, bool SCALE>
__device__ inline void mm_half2(const float* __restrict__ tw,
                                const float* __restrict__ L0,
                                const float* __restrict__ L1,
                                float* __restrict__ O0,
                                float* __restrict__ O1,
                                int w4, int lane)
{
  float a0[MPW], a1[MPW];
  #pragma unroll
  for (int m=0;m<MPW;++m) { a0[m]=0.f; a1[m]=0.f; }
  const int inBase = SIN ? 33 : 0;
  #pragma unroll 8
  for (int i=0;i<K;++i) {
    float lv0 = L0[(inBase+i)*P65 + lane];
    float lv1 = L1[(inBase+i)*P65 + lane];
    const float* ti = tw + i*MPW;
    #pragma unroll
    for (int m=0;m<MPW;++m) {
      float tv = ti[m];
      a0[m] = fmaf(tv, lv0, a0[m]);
      a1[m] = fmaf(tv, lv1, a1[m]);
    }
  }
  #pragma unroll
  for (int m=0;m<MPW;++m) {
    int r = SIN ? (33 + w4 + 4*m) : (w4 + 4*m);
    if (SIN || r <= 32) {
      float v0 = a0[m], v1 = a1[m];
      if (SCALE) { float mp = g_Mp[r*P65 + lane]; v0 *= mp; v1 *= mp; }
      O0[lane*P65 + r] = v0;
      O1[lane*P65 + r] = v1;
    }
  }
}

template<bool SCALE>
__device__ inline void mm_stage2(const float* __restrict__ L0, const float* __restrict__ L1,
                                 float* __restrict__ O0, float* __restrict__ O1,
                                 int wvu, int lane)
{
  if (wvu < 4) mm_half2<33,9,false,SCALE>(g_Rc + wvu*(33*9), L0, L1, O0, O1, wvu, lane);
  else         mm_half2<32,8,true ,SCALE>(g_Rs + (wvu-4)*(32*8), L0, L1, O0, O1, wvu-4, lane);
}

// Parity fold read (analysis EO pass): even rows 0..32, odd rows 33..64.
__device__ inline float eo_fold(const float* __restrict__ Ab, int r, int lane) {
  if (r == 0) return Ab[lane];
  if (r <= 32) { int p = (r==1)?0:(65-r); return Ab[r*P65+lane] + Ab[p*P65+lane]; }
  int i = r-32; int p = (i==1)?0:(65-i); return Ab[i*P65+lane] - Ab[p*P65+lane];
}

// ---- stencil: psi from LDS (plain reads), x re-read from global (L2-hot) + shuffles ----
__device__ inline void stencil_img(const float* __restrict__ A_,
                                   const float* __restrict__ xb,
                                   float mu, float id2,
                                   float* __restrict__ op,
                                   int wvu, int lane, bool store)
{
  const int c = lane, cm = (c+63)&63, cp = (c+1)&63;
  const int j0 = wvu*8, jm0 = (j0+63)&63, jp8 = (j0+8)&63;

  float xg[10];
  xg[0] = xb[jm0*64 + c];
  #pragma unroll
  for (int k=0;k<8;++k) xg[k+1] = xb[(j0+k)*64 + c];
  xg[9] = xb[jp8*64 + c];

  float xm_c = xg[0], xm_m = shflx(xm_c, cm), xm_p = shflx(xm_c, cp);
  float xc_c = xg[1], xc_m = shflx(xc_c, cm), xc_p = shflx(xc_c, cp);
  float pm_m = A_[jm0*P65+cm], pm_c = A_[jm0*P65+c], pm_p = A_[jm0*P65+cp];
  float pc_m = A_[j0 *P65+cm], pc_c = A_[j0 *P65+c], pc_p = A_[j0 *P65+cp];

  #pragma unroll
  for (int m=0;m<8;++m) {
    int j = j0 + m, jp = (j+1)&63;
    float xn_c = xg[m+2];
    float xn_m = shflx(xn_c, cm), xn_p = shflx(xn_c, cp);
    float pn_m = A_[jp*P65+cm], pn_c = A_[jp*P65+c], pn_p = A_[jp*P65+cp];

    float J1 = (pn_c - pm_c)*(xc_p - xc_m) - (pc_p - pc_m)*(xn_c - xm_c);
    float J2 = xc_p*(pn_p - pm_p) - xc_m*(pn_m - pm_m)
             - xn_c*(pn_p - pn_m) + xm_c*(pm_p - pm_m);
    float J3 = xn_p*(pn_c - pc_p) - xm_m*(pc_m - pm_c)
             - xn_m*(pn_c - pc_m) + xm_p*(pc_p - pm_c);
    float lap = (xm_c + xn_c + xc_m + xc_p + xn_m - 4.0f*xc_c) * id2;

    if (store) op[j*64 + c] = -(J1 + J2 + J3)*(0.25f/3.0f) + mu*lap;

    xm_m=xc_m; xm_c=xc_c; xm_p=xc_p;  pm_m=pc_m; pm_c=pc_c; pm_p=pc_p;
    xc_m=xn_m; xc_c=xn_c; xc_p=xn_p;  pc_m=pn_m; pc_c=pn_c; pc_p=pn_p;
  }
}

__global__ void __launch_bounds__(512) pde_main(const float* __restrict__ y0,
                                                const int*   __restrict__ env,
                                                const float* __restrict__ params,
                                                float*       __restrict__ out,
                                                int B)
{
  __shared__ float A0[P65*P65];
  __shared__ float B0[P65*P65];
  __shared__ float A1[P65*P65];
  __shared__ float B1[P65*P65];

  const int t    = threadIdx.x;
  const int lane = t & 63;
  const int wvu  = __builtin_amdgcn_readfirstlane(t >> 6);

  const int b0  = 2*blockIdx.x;
  const int b1r = 2*blockIdx.x + 1;
  const bool has2 = (b1r < B);
  const int b1 = has2 ? b1r : b0;

  const int   e0 = env[b0], e1 = env[b1];
  const float mu0 = params[2*e0], mu1 = params[2*e1];
  const float fdx0 = c_DOMAIN[e0] * (float)(3.14159265358979323846/64.0);
  const float fdx1 = c_DOMAIN[e1] * (float)(3.14159265358979323846/64.0);
  const float idx2_0 = 1.0f/(fdx0*fdx0);
  const float idx2_1 = 1.0f/(fdx1*fdx1);

  const float* xb0 = y0 + (size_t)b0*4096;
  const float* xb1 = y0 + (size_t)b1*4096;

  // ---- Phase L: W = -x -> A (coalesced; no register retention) ----
  #pragma unroll
  for (int k=0;k<8;++k) {
    int idx = k*512 + t;
    int j = idx >> 6;
    A0[j*P65 + lane] = -xb0[idx];
    A1[j*P65 + lane] = -xb1[idx];
  }
  __syncthreads();

  // ---- Phase EO1: parity fold over spatial rows : A -> B ----
  #pragma unroll
  for (int m=0;m<9;++m) {
    int r = wvu + 8*m;
    if (r <= 64) {
      B0[r*P65 + lane] = eo_fold(A0, r, lane);
      B1[r*P65 + lane] = eo_fold(A1, r, lane);
    }
  }
  __syncthreads();

  // ---- Phase S1: dim-1 analysis : B -> A transposed ----
  mm_stage2<false>(B0, B1, A0, A1, wvu, lane);
  __syncthreads();

  // ---- Phase EO2: parity fold over spatial cols : A -> B ; col-64 tail on waves 5-7 ----
  #pragma unroll
  for (int m=0;m<9;++m) {
    int r = wvu + 8*m;
    if (r <= 64) {
      B0[r*P65 + lane] = eo_fold(A0, r, lane);
      B1[r*P65 + lane] = eo_fold(A1, r, lane);
    }
  }
  if (t >= 320 && t < 450) {
    int u = t - 320;
    const float* Ax = (u < 65) ? A0 : A1;
    float* Bx = (u < 65) ? B0 : B1;
    int r = (u < 65) ? u : (u - 65);
    float v;
    if (r == 0)      v = Ax[64];
    else if (r <= 32){ int p = (r==1)?0:(65-r); v = Ax[r*P65+64] + Ax[p*P65+64]; }
    else             { int i = r-32; int p = (i==1)?0:(65-i); v = Ax[i*P65+64] - Ax[p*P65+64]; }
    Bx[r*P65 + 64] = v;
  }
  __syncthreads();

  // ---- Phase S2: dim-2 analysis x Mp : B -> A ; row-64 tail on waves 5-7 ----
  mm_stage2<true>(B0, B1, A0, A1, wvu, lane);
  if (t >= 320 && t < 450) {
    int u = t - 320;
    const float* Bx = (u < 65) ? B0 : B1;
    float* Ax = (u < 65) ? A0 : A1;
    int r = (u < 65) ? u : (u - 65);
    float acc = 0.f;
    if (r <= 32) { for (int i=0;i<33;++i) acc = fmaf(g_G[r*33+i], Bx[i*P65+64], acc); }
    else         { for (int i=1;i<33;++i) acc = fmaf(g_G[r*33+i], Bx[(32+i)*P65+64], acc); }
    Ax[64*P65 + r] = acc * g_Mp[64*P65 + r];
  }
  __syncthreads();

  // ---- Phase S3: dim-1 synthesis halves : A -> B ; row-64 tail on waves 5-7 ----
  mm_stage2<false>(A0, A1, B0, B1, wvu, lane);
  if (t >= 320 && t < 450) {
    int u = t - 320;
    const float* Ax = (u < 65) ? A0 : A1;
    float* Bx = (u < 65) ? B0 : B1;
    int r = (u < 65) ? u : (u - 65);
    float acc = 0.f;
    if (r <= 32) { for (int i=0;i<33;++i) acc = fmaf(g_G[r*33+i], Ax[i*P65+64], acc); }
    else         { for (int i=1;i<33;++i) acc = fmaf(g_G[r*33+i], Ax[(32+i)*P65+64], acc); }
    Bx[64*P65 + r] = acc;
  }
  __syncthreads();

  // ---- Phase C3: combine halves along rows : B[k2][r'] -> A[k2][j1] ----
  #pragma unroll
  for (int m=0;m<9;++m) {
    int r = wvu + 8*m;
    if (r <= 64) {
      int j1 = lane; float v0, v1;
      if (j1 == 0)      { v0 = B0[r*P65]; v1 = B1[r*P65]; }
      else if (j1 <= 32){ v0 = B0[r*P65 + j1] + B0[r*P65 + 32 + j1]; v1 = B1[r*P65 + j1] + B1[r*P65 + 32 + j1]; }
      else              { v0 = B0[r*P65 + 65 - j1] - B0[r*P65 + 97 - j1]; v1 = B1[r*P65 + 65 - j1] - B1[r*P65 + 97 - j1]; }
      A0[r*P65 + lane] = v0;
      A1[r*P65 + lane] = v1;
    }
  }
  __syncthreads();

  // ---- Phase S4: dim-2 synthesis halves : A -> B transposed ----
  mm_stage2<false>(A0, A1, B0, B1, wvu, lane);
  __syncthreads();

  // ---- Phase C4: combine halves -> psi in A[j1][j2] ----
  #pragma unroll
  for (int m=0;m<8;++m) {
    int r = wvu + 8*m;
    int j2 = lane; float v0, v1;
    if (j2 == 0)      { v0 = B0[r*P65]; v1 = B1[r*P65]; }
    else if (j2 <= 32){ v0 = B0[r*P65 + j2] + B0[r*P65 + 32 + j2]; v1 = B1[r*P65 + j2] + B1[r*P65 + 32 + j2]; }
    else              { v0 = B0[r*P65 + 65 - j2] - B0[r*P65 + 97 - j2]; v1 = B1[r*P65 + 65 - j2] - B1[r*P65 + 97 - j2]; }
    A0[r*P65 + lane] = v0;
    A1[r*P65 + lane] = v1;
  }
  __syncthreads();

  // ---- Phase ST: stencil; psi from LDS, x re-read from global (L2-hot) ----
  stencil_img(A0, xb0, mu0, idx2_0, out + (size_t)b0*4096, wvu, lane, true);
  stencil_img(A1, xb1, mu1, idx2_1, out + (size_t)b1*4096, wvu, lane, has2);
}

extern "C" void kernel_launch(void* const* d_in, const int* in_sizes, int n_in,
                              void* d_out, int out_size, void* d_ws, size_t ws_size,
                              hipStream_t stream) {
  const float* y0     = (const float*)d_in[1];
  const int*   env    = (const int*)  d_in[2];
  const float* params = (const float*)d_in[3];
  float*       out    = (float*)d_out;
  int B = in_sizes[1] / 4096;
  int nb = (B + 1) / 2;

  init_tables<<<96, 256, 0, stream>>>();
  pde_main<<<nb, 512, 0, stream>>>(y0, env, params, out, B);
}

// Round 9
// 58.420 us; speedup vs baseline: 1.5387x; 1.2209x over previous
//
#include <hip/hip_runtime.h>
#include <math.h>

#define P65   65
#define LTSTR 72                 // u16 per row (144 B, 16B-multiple)
#define LTROWS 80
#define PLANE (LTROWS*LTSTR)     // 5760 u16 = 11520 B per plane

// ---- device tables (built by init_tables each launch; deterministic) ----
// A-fragments for mfma_f32_16x16x32_bf16, hi/lo bf16 planes. 18 blocks of 512:
//   blocks 0..9  : analysis table Gf (wrap-folded), tiles (mt0..4, kt0..1)
//   blocks 10..17: synthesis table Gt[j][k1]=G[k1][j], tiles (mt0..3, kt0..1)
//   within block: lane l, elem e -> Tbl[16*mt + (l&15)][32*kt + 8*(l>>4) + e]
__device__ __align__(16) ushort gAfragH[18*512];
__device__ __align__(16) ushort gAfragL[18*512];
__device__ float  g_Mp[65*65];    // spectral multiplier (norms folded), symmetric, [0][0]=0
__device__ float  g64tab[64];     // G[64][j] = sin(2*pi*32*j/65)

__device__ __constant__ float c_DOMAIN[8] = {0.75f,1.0f,0.75f,1.0f,0.75f,1.0f,0.75f,1.0f};

__device__ inline ushort f2bf(float f) {          // RNE float -> bf16 bits
  unsigned u = __float_as_uint(f);
  return (ushort)((u + 0x7FFFu + ((u >> 16) & 1u)) >> 16);
}
__device__ inline float bf2f(ushort h) { return __uint_as_float(((unsigned)h) << 16); }

// G[r][i]: r<=32 -> cos(2*pi*r*i/65) ; r>=33 -> sin(2*pi*(r-32)*i/65)
__device__ inline double Gval(int r, int i) {
  int m = (r <= 32) ? r : (r - 32);
  int prod = (m * (i % 65)) % 65;
  double ang = 6.283185307179586476925286766559 * (double)prod / 65.0;
  return (r <= 32) ? cos(ang) : sin(ang);
}
// folded analysis: Gf[r][i] = G[r][i] + (i==0)*G[r][64]
__device__ inline double Gfold(int r, int i) {
  double v = Gval(r, i);
  if (i == 0) v += Gval(r, 64);
  return v;
}

__global__ void init_tables() {
  int tid = blockIdx.x*blockDim.x + threadIdx.x;
  int nth = gridDim.x*blockDim.x;
  for (int idx = tid; idx < 18*512; idx += nth) {
    int blk = idx >> 9, rem = idx & 511;
    int lane = rem >> 3, e = rem & 7;
    int i16 = lane & 15, kg = lane >> 4;
    float v = 0.f;
    if (blk < 10) {
      int mt = blk >> 1, kt = blk & 1;
      int r = 16*mt + i16;            // freq row (<65)
      int i = 32*kt + 8*kg + e;       // spatial col (<64)
      if (r < 65 && i < 64) v = (float)Gfold(r, i);
    } else {
      int b2 = blk - 10;
      int mt = b2 >> 1, kt = b2 & 1;
      int j  = 16*mt + i16;           // spatial row (<64)
      int k1 = 32*kt + 8*kg + e;      // freq col (<64; k=64 via rank-1)
      if (j < 64 && k1 < 64) v = (float)Gval(k1, j);
    }
    ushort h = f2bf(v);
    gAfragH[idx] = h;
    gAfragL[idx] = f2bf(v - bf2f(h));
  }
  for (int idx = tid; idx < 65*65; idx += nth) {
    int k1 = idx/65, k2 = idx%65;
    float v = 0.f;
    if (k1 | k2) {
      double n1 = (k1==0)?(1.0/65.0):(2.0/65.0);
      double n2 = (k2==0)?(1.0/65.0):(2.0/65.0);
      int m1 = (k1<=32)?k1:(k1-32), m2 = (k2<=32)?k2:(k2-32);
      double b1 = 6.283185307179586476925286766559*(double)m1/65.0;
      double b2 = 6.283185307179586476925286766559*(double)m2/65.0;
      v = (float)(-(n1*n2)/(b1*b1 + b2*b2));
    }
    g_Mp[idx] = v;
  }
  for (int idx = tid; idx < 64; idx += nth)
    g64tab[idx] = (float)Gval(64, idx);
}

typedef __attribute__((ext_vector_type(8))) short bf16x8;
typedef __attribute__((ext_vector_type(4))) float f32x4;

// One transform stage as MFMA tiles, hi/lo split operands.
// O[m][n] = sum_k Tbl[m][k] * Lin[n][k]; Lin row-major is exactly the B-fragment layout.
// RK: add rank-1 k=64 term g64tab[m] * Lin[n][64].
// PSI: write fp32 transposed (psi[j1=n][j2=m]); else hi/lo bf16 row-major [m][n].
template<int MT, int NT, int MR, int NR, int TBLOFF, bool SCALE, bool RK, bool PSI>
__device__ inline void stage(const ushort* __restrict__ LinH,
                             const ushort* __restrict__ LinL,
                             ushort* __restrict__ LoutH,
                             ushort* __restrict__ LoutL,
                             float* __restrict__ psiout,
                             int wvu, int lane)
{
  const int lg = lane >> 4, li = lane & 15;
  for (int tile = wvu; tile < MT*NT; tile += 8) {
    int mt = tile / NT, nt = tile % NT;
    int mbase = 16*mt + 4*lg;
    int n = 16*nt + li;
    f32x4 acc = {0.f, 0.f, 0.f, 0.f};
    #pragma unroll
    for (int kt = 0; kt < 2; ++kt) {
      int toff = (TBLOFF + mt*2 + kt)*512 + lane*8;
      bf16x8 ah = *(const bf16x8*)(gAfragH + toff);
      bf16x8 al = *(const bf16x8*)(gAfragL + toff);
      int boff = n*LTSTR + 32*kt + 8*lg;
      bf16x8 bh = *(const bf16x8*)(LinH + boff);
      bf16x8 bl = *(const bf16x8*)(LinL + boff);
      acc = __builtin_amdgcn_mfma_f32_16x16x32_bf16(ah, bh, acc, 0, 0, 0);
      acc = __builtin_amdgcn_mfma_f32_16x16x32_bf16(ah, bl, acc, 0, 0, 0);
      acc = __builtin_amdgcn_mfma_f32_16x16x32_bf16(al, bh, acc, 0, 0, 0);
    }
    float rkB = 0.f;
    if (RK) rkB = bf2f(LinH[n*LTSTR + 64]) + bf2f(LinL[n*LTSTR + 64]);
    #pragma unroll
    for (int r = 0; r < 4; ++r) {
      int m = mbase + r;
      if (m < MR && n < NR) {
        float v = acc[r];
        if (SCALE) v *= g_Mp[m*65 + n];
        if (RK)    v = fmaf(g64tab[m], rkB, v);
        if (PSI) {
          psiout[n*P65 + m] = v;          // transposed: Ppsi[j1][j2]
        } else {
          ushort h = f2bf(v);
          LoutH[m*LTSTR + n] = h;
          LoutL[m*LTSTR + n] = f2bf(v - bf2f(h));
        }
      }
    }
  }
}

__device__ inline float shflx(float v, int srclane) { return __shfl(v, srclane, 64); }

// Stencil: psi (=P) from LDS fp32 (stride 65), x re-read from global (L2-hot).
__device__ inline void stencil_img(const float* __restrict__ A_,
                                   const float* __restrict__ xb,
                                   float mu, float id2,
                                   float* __restrict__ op,
                                   int wvu, int lane)
{
  const int c = lane, cm = (c+63)&63, cp = (c+1)&63;
  const int j0 = wvu*8, jm0 = (j0+63)&63, jp8 = (j0+8)&63;

  float xg[10];
  xg[0] = xb[jm0*64 + c];
  #pragma unroll
  for (int k=0;k<8;++k) xg[k+1] = xb[(j0+k)*64 + c];
  xg[9] = xb[jp8*64 + c];

  float xm_c = xg[0], xm_m = shflx(xm_c, cm), xm_p = shflx(xm_c, cp);
  float xc_c = xg[1], xc_m = shflx(xc_c, cm), xc_p = shflx(xc_c, cp);
  float pm_m = A_[jm0*P65+cm], pm_c = A_[jm0*P65+c], pm_p = A_[jm0*P65+cp];
  float pc_m = A_[j0 *P65+cm], pc_c = A_[j0 *P65+c], pc_p = A_[j0 *P65+cp];

  #pragma unroll
  for (int m=0;m<8;++m) {
    int j = j0 + m, jp = (j+1)&63;
    float xn_c = xg[m+2];
    float xn_m = shflx(xn_c, cm), xn_p = shflx(xn_c, cp);
    float pn_m = A_[jp*P65+cm], pn_c = A_[jp*P65+c], pn_p = A_[jp*P65+cp];

    float J1 = (pn_c - pm_c)*(xc_p - xc_m) - (pc_p - pc_m)*(xn_c - xm_c);
    float J2 = xc_p*(pn_p - pm_p) - xc_m*(pn_m - pm_m)
             - xn_c*(pn_p - pn_m) + xm_c*(pm_p - pm_m);
    float J3 = xn_p*(pn_c - pc_p) - xm_m*(pc_m - pm_c)
             - xn_m*(pn_c - pc_m) + xm_p*(pc_p - pm_c);
    float lap = (xm_c + xn_c + xc_m + xc_p + xn_m - 4.0f*xc_c) * id2;

    op[j*64 + c] = -(J1 + J2 + J3)*(0.25f/3.0f) + mu*lap;

    xm_m=xc_m; xm_c=xc_c; xm_p=xc_p;  pm_m=pc_m; pm_c=pc_c; pm_p=pc_p;
    xc_m=xn_m; xc_c=xn_c; xc_p=xn_p;  pc_m=pn_m; pc_c=pn_c; pc_p=pn_p;
  }
}

__global__ void __launch_bounds__(512) pde_main(const float* __restrict__ y0,
                                                const int*   __restrict__ env,
                                                const float* __restrict__ params,
                                                float*       __restrict__ out)
{
  __shared__ __align__(16) ushort Lsh[4*PLANE];   // AH | AL | BH | BL ; psi overlays A at S4
  ushort* AH = Lsh;
  ushort* AL = Lsh + PLANE;
  ushort* BH = Lsh + 2*PLANE;
  ushort* BL = Lsh + 3*PLANE;
  float*  Ppsi = (float*)Lsh;                     // 64*65*4 B = 16640 <= 23040 (A planes)

  const int b    = blockIdx.x;
  const int t    = threadIdx.x;
  const int lane = t & 63;
  const int wvu  = __builtin_amdgcn_readfirstlane(t >> 6);

  const int   e       = env[b];
  const float mu      = params[2*e];
  const float fdx     = c_DOMAIN[e] * (float)(3.14159265358979323846/64.0);
  const float inv_dx2 = 1.0f/(fdx*fdx);

  const float* xb = y0 + (size_t)b*4096;

  // ---- Phase L: zero rows 65..79 of all planes; load W = -x transposed, hi/lo split ----
  for (int i = t; i < 15*LTSTR; i += 512) {
    AH[65*LTSTR + i] = 0;  AL[65*LTSTR + i] = 0;
    BH[65*LTSTR + i] = 0;  BL[65*LTSTR + i] = 0;
  }
  #pragma unroll
  for (int k=0;k<8;++k) {
    int idx = k*512 + t;
    int j = idx >> 6, c = idx & 63;
    float v = -xb[idx];
    ushort h = f2bf(v);
    AH[c*LTSTR + j] = h;
    AL[c*LTSTR + j] = f2bf(v - bf2f(h));
  }
  __syncthreads();

  // ---- S1: A1[k1][c2] = sum_j Gf[k1][j]*W[j][c2]            (M=65,N=64,K=64 folded)
  stage<5,4,65,64, 0,false,false,false>(AH,AL, BH,BL, nullptr, wvu, lane);
  __syncthreads();
  // ---- S2: S2out[k2][k1] = Mp .* sum_c2 Gf[k2][c2]*A1[k1][c2] (M=65,N=65,K=64 folded)
  stage<5,5,65,65, 0,true ,false,false>(BH,BL, AH,AL, nullptr, wvu, lane);
  __syncthreads();
  // ---- S3: V[j1][k2] = sum_k1 G[k1][j1]*spec[k1][k2]          (M=64,N=65; rank-1 k1=64)
  stage<4,5,64,65,10,false,true ,false>(AH,AL, BH,BL, nullptr, wvu, lane);
  __syncthreads();
  // ---- S4: psi[j1][j2] = sum_k2 G[k2][j2]*V[j1][k2]           (M=64,N=64; rank-1 k2=64)
  //      O[m=j2][n=j1] -> transposed fp32 write into Ppsi[j1][j2] (overlays dead A planes)
  stage<4,4,64,64,10,false,true ,true >(BH,BL, nullptr,nullptr, Ppsi, wvu, lane);
  __syncthreads();

  // ---- stencil ----
  stencil_img(Ppsi, xb, mu, inv_dx2, out + (size_t)b*4096, wvu, lane);
}

extern "C" void kernel_launch(void* const* d_in, const int* in_sizes, int n_in,
                              void* d_out, int out_size, void* d_ws, size_t ws_size,
                              hipStream_t stream) {
  const float* y0     = (const float*)d_in[1];
  const int*   env    = (const int*)  d_in[2];
  const float* params = (const float*)d_in[3];
  float*       out    = (float*)d_out;
  int B = in_sizes[1] / 4096;

  init_tables<<<32, 256, 0, stream>>>();
  pde_main<<<B, 512, 0, stream>>>(y0, env, params, out);
}

// Round 10
// 54.839 us; speedup vs baseline: 1.6392x; 1.0653x over previous
//
#include <hip/hip_runtime.h>
#include <math.h>

#define P65 65
#define PLANE_U16 5248        // 5120 frag + 80 side + 48 pad (10496 B, 16B-multiple)
#define SIDE_OFF  5120

// ---- device tables (built by init_tables each launch; deterministic) ----
// A-fragments for mfma_f32_16x16x32_bf16, hi/lo bf16 planes. 18 blocks of 512:
//   blocks 0..9  : analysis table Gf (wrap-folded), tiles (mt0..4, kt0..1)
//   blocks 10..17: synthesis table Gt[j][k1]=G[k1][j], tiles (mt0..3, kt0..1)
//   within block: lane l, elem e -> Tbl[16*mt + (l&15)][32*kt + 8*(l>>4) + e]
__device__ __align__(16) ushort gAfragH[18*512];
__device__ __align__(16) ushort gAfragL[18*512];
__device__ float  g_MpN[65*65];   // NEGATED spectral multiplier (sign folded: we store x, not -x)
__device__ float  g64tab[64];     // G[64][j] = sin(2*pi*32*j/65)

__device__ __constant__ float c_DOMAIN[8] = {0.75f,1.0f,0.75f,1.0f,0.75f,1.0f,0.75f,1.0f};

__device__ inline ushort f2bf(float f) {          // RNE float -> bf16 bits
  unsigned u = __float_as_uint(f);
  return (ushort)((u + 0x7FFFu + ((u >> 16) & 1u)) >> 16);
}
__device__ inline float bf2f(ushort h) { return __uint_as_float(((unsigned)h) << 16); }

// G[r][i]: r<=32 -> cos(2*pi*r*i/65) ; r>=33 -> sin(2*pi*(r-32)*i/65)
__device__ inline double Gval(int r, int i) {
  int m = (r <= 32) ? r : (r - 32);
  int prod = (m * (i % 65)) % 65;
  double ang = 6.283185307179586476925286766559 * (double)prod / 65.0;
  return (r <= 32) ? cos(ang) : sin(ang);
}
__device__ inline double Gfold(int r, int i) {    // wrap-fold: += G[r][64] at i==0
  double v = Gval(r, i);
  if (i == 0) v += Gval(r, 64);
  return v;
}

__global__ void init_tables() {
  int tid = blockIdx.x*blockDim.x + threadIdx.x;
  int nth = gridDim.x*blockDim.x;
  for (int idx = tid; idx < 18*512; idx += nth) {
    int blk = idx >> 9, rem = idx & 511;
    int lane = rem >> 3, e = rem & 7;
    int i16 = lane & 15, kg = lane >> 4;
    float v = 0.f;
    if (blk < 10) {
      int mt = blk >> 1, kt = blk & 1;
      int r = 16*mt + i16;            // freq row (<65)
      int i = 32*kt + 8*kg + e;       // spatial col (<64)
      if (r < 65 && i < 64) v = (float)Gfold(r, i);
    } else {
      int b2 = blk - 10;
      int mt = b2 >> 1, kt = b2 & 1;
      int j  = 16*mt + i16;           // spatial row (<64)
      int k1 = 32*kt + 8*kg + e;      // freq col (<64; k=64 via rank-1)
      if (j < 64 && k1 < 64) v = (float)Gval(k1, j);
    }
    ushort h = f2bf(v);
    gAfragH[idx] = h;
    gAfragL[idx] = f2bf(v - bf2f(h));
  }
  for (int idx = tid; idx < 65*65; idx += nth) {
    int k1 = idx/65, k2 = idx%65;
    float v = 0.f;
    if (k1 | k2) {
      double n1 = (k1==0)?(1.0/65.0):(2.0/65.0);
      double n2 = (k2==0)?(1.0/65.0):(2.0/65.0);
      int m1 = (k1<=32)?k1:(k1-32), m2 = (k2<=32)?k2:(k2-32);
      double b1 = 6.283185307179586476925286766559*(double)m1/65.0;
      double b2 = 6.283185307179586476925286766559*(double)m2/65.0;
      v = (float)((n1*n2)/(b1*b1 + b2*b2));     // NEGATED vs true Mp
    }
    g_MpN[idx] = v;
  }
  for (int idx = tid; idx < 64; idx += nth)
    g64tab[idx] = (float)Gval(64, idx);
}

typedef __attribute__((ext_vector_type(8))) short bf16x8;
typedef __attribute__((ext_vector_type(4))) float f32x4;

// One transform stage as MFMA tiles, hi/lo split operands, fragment-layout LDS planes.
// O[m][n] = sum_k Tbl[m][k] * Lin[n][k]  + optional rank-1 (k=64 sidecar).
// Frag layout: element (row n', col k') at (n'>>4)*2+(k'>>5) block, lane 16*((k'>>3)&3)+(n'&15), e=k'&7.
// B-read for tile (nt,kt) = LinX + (nt*2+kt)*512 + lane*8  -> lane-contiguous, conflict-free.
template<int MT, int NT, int MR, int NR, int TBLOFF, bool SCALE, bool RK, bool PSI>
__device__ inline void stage(const ushort* __restrict__ LinH,
                             const ushort* __restrict__ LinL,
                             ushort* __restrict__ LoutH,
                             ushort* __restrict__ LoutL,
                             float* __restrict__ psiout,
                             int wvu, int lane)
{
  const int lg = lane >> 4, li = lane & 15;
  for (int tile = wvu; tile < MT*NT; tile += 8) {
    int mt = tile / NT, nt = tile - mt*NT;
    int n = 16*nt + li;
    f32x4 acc = {0.f, 0.f, 0.f, 0.f};
    #pragma unroll
    for (int kt = 0; kt < 2; ++kt) {
      int toff = (TBLOFF + mt*2 + kt)*512 + lane*8;
      bf16x8 ah = *(const bf16x8*)(gAfragH + toff);
      bf16x8 al = *(const bf16x8*)(gAfragL + toff);
      int boff = (nt*2 + kt)*512 + lane*8;
      bf16x8 bh = *(const bf16x8*)(LinH + boff);
      bf16x8 bl = *(const bf16x8*)(LinL + boff);
      acc = __builtin_amdgcn_mfma_f32_16x16x32_bf16(ah, bh, acc, 0, 0, 0);
      acc = __builtin_amdgcn_mfma_f32_16x16x32_bf16(ah, bl, acc, 0, 0, 0);
      acc = __builtin_amdgcn_mfma_f32_16x16x32_bf16(al, bh, acc, 0, 0, 0);
    }
    float rkB = 0.f;
    if (RK) rkB = bf2f(LinH[SIDE_OFF + n]) + bf2f(LinL[SIDE_OFF + n]);
    int mbase = 16*mt + 4*lg;
    int wbase = (mt*2 + (nt>>1))*512 + ((2*nt + (li>>3))&3)*128 + (li&7);
    #pragma unroll
    for (int r = 0; r < 4; ++r) {
      int m = mbase + r;
      if (m < MR && n < NR) {
        float v = acc[r];
        if (SCALE) v *= g_MpN[m*65 + n];
        if (RK)    v = fmaf(g64tab[m], rkB, v);
        if (PSI) {
          psiout[n*P65 + m] = v;               // transposed: Ppsi[j1][j2]
        } else if (NT == 5 && nt == 4) {       // n==64 (only li==0 passes n<NR)
          ushort h = f2bf(v);
          LoutH[SIDE_OFF + m] = h;
          LoutL[SIDE_OFF + m] = f2bf(v - bf2f(h));
        } else {
          ushort h = f2bf(v);
          LoutH[wbase + (4*lg + r)*8] = h;
          LoutL[wbase + (4*lg + r)*8] = f2bf(v - bf2f(h));
        }
      }
    }
  }
}

__device__ inline float shflx(float v, int srclane) { return __shfl(v, srclane, 64); }

__global__ void __launch_bounds__(512) pde_main(const float* __restrict__ y0,
                                                const int*   __restrict__ env,
                                                const float* __restrict__ params,
                                                float*       __restrict__ out)
{
  // [P0H | P0L | P1H | P1L]; psi (fp32, 16640 B) overlays P0H+P0L (20992 B, dead at S4)
  __shared__ __align__(16) ushort Lsh[4*PLANE_U16];
  ushort* PH0 = Lsh;
  ushort* PL0 = Lsh + PLANE_U16;
  ushort* PH1 = Lsh + 2*PLANE_U16;
  ushort* PL1 = Lsh + 3*PLANE_U16;
  float*  Ppsi = (float*)Lsh;

  const int b    = blockIdx.x;
  const int t    = threadIdx.x;
  const int lane = t & 63;
  const int wvu  = __builtin_amdgcn_readfirstlane(t >> 6);

  const int   e       = env[b];
  const float mu      = params[2*e];
  const float fdx     = c_DOMAIN[e] * (float)(3.14159265358979323846/64.0);
  const float inv_dx2 = 1.0f/(fdx*fdx);

  const float* xb = y0 + (size_t)b*4096;

  // ---- Phase L: wave owns rows 8wvu..8wvu+7, col=lane. Store x (sign folded into MpN)
  //      transposed into frag layout: element (row=lane, col=j=8wvu+k) -> one b128 write/plane.
  float xr[8];
  bf16x8 hv, lv;
  #pragma unroll
  for (int k=0;k<8;++k) {
    float v = xb[(8*wvu + k)*64 + lane];
    xr[k] = v;
    ushort h = f2bf(v);
    hv[k] = (short)h;
    lv[k] = (short)f2bf(v - bf2f(h));
  }
  {
    int wb = ((lane>>4)*2 + (wvu>>2))*512 + ((wvu&3)*16 + (lane&15))*8;
    *(bf16x8*)(PH0 + wb) = hv;
    *(bf16x8*)(PL0 + wb) = lv;
  }
  __syncthreads();

  // ---- S1: A1[k1][c2] = sum_j Gf[k1][j]*x[j][c2]              (M=65,N=64,K=64 folded)
  stage<5,4,65,64, 0,false,false,false>(PH0,PL0, PH1,PL1, nullptr, wvu, lane);
  __syncthreads();
  // ---- S2: spec[k2][k1] = MpN .* sum_c2 Gf[k2][c2]*A1[k1][c2] (M=65,N=65; side[k2]=spec[64-col])
  stage<5,5,65,65, 0,true ,false,false>(PH1,PL1, PH0,PL0, nullptr, wvu, lane);
  __syncthreads();
  // ---- S3: V[j1][k2] = sum_k1 G[k1][j1]*spec[k1][k2]           (M=64,N=65; rank-1 k1=64)
  stage<4,5,64,65,10,false,true ,false>(PH0,PL0, PH1,PL1, nullptr, wvu, lane);
  __syncthreads();
  // ---- S4: psi[j1][j2] = sum_k2 G[k2][j2]*V[j1][k2]            (M=64,N=64; rank-1 k2=64)
  stage<4,4,64,64,10,false,true ,true >(PH1,PL1, nullptr,nullptr, Ppsi, wvu, lane);
  __syncthreads();

  // ---- stencil: psi from LDS fp32; own x rows from regs, 2 boundary rows from global (L2-hot)
  {
    const int c = lane, cm = (c+63)&63, cp = (c+1)&63;
    const int j0 = wvu*8, jm0 = (j0+63)&63, jp8 = (j0+8)&63;
    float xbm = xb[jm0*64 + c];
    float xbp = xb[jp8*64 + c];
    float* op = out + (size_t)b*4096;

    float xm_c = xbm,   xm_m = shflx(xm_c, cm), xm_p = shflx(xm_c, cp);
    float xc_c = xr[0], xc_m = shflx(xc_c, cm), xc_p = shflx(xc_c, cp);
    float pm_m = Ppsi[jm0*P65+cm], pm_c = Ppsi[jm0*P65+c], pm_p = Ppsi[jm0*P65+cp];
    float pc_m = Ppsi[j0 *P65+cm], pc_c = Ppsi[j0 *P65+c], pc_p = Ppsi[j0 *P65+cp];

    #pragma unroll
    for (int m=0;m<8;++m) {
      int j = j0 + m, jp = (j+1)&63;
      float xn_c = (m < 7) ? xr[m+1] : xbp;
      float xn_m = shflx(xn_c, cm), xn_p = shflx(xn_c, cp);
      float pn_m = Ppsi[jp*P65+cm], pn_c = Ppsi[jp*P65+c], pn_p = Ppsi[jp*P65+cp];

      float J1 = (pn_c - pm_c)*(xc_p - xc_m) - (pc_p - pc_m)*(xn_c - xm_c);
      float J2 = xc_p*(pn_p - pm_p) - xc_m*(pn_m - pm_m)
               - xn_c*(pn_p - pn_m) + xm_c*(pm_p - pm_m);
      float J3 = xn_p*(pn_c - pc_p) - xm_m*(pc_m - pm_c)
               - xn_m*(pn_c - pc_m) + xm_p*(pc_p - pm_c);
      float lap = (xm_c + xn_c + xc_m + xc_p + xn_m - 4.0f*xc_c) * inv_dx2;

      op[j*64 + c] = -(J1 + J2 + J3)*(0.25f/3.0f) + mu*lap;

      xm_m=xc_m; xm_c=xc_c; xm_p=xc_p;  pm_m=pc_m; pm_c=pc_c; pm_p=pc_p;
      xc_m=xn_m; xc_c=xn_c; xc_p=xn_p;  pc_m=pn_m; pc_c=pn_c; pc_p=pn_p;
    }
  }
}

extern "C" void kernel_launch(void* const* d_in, const int* in_sizes, int n_in,
                              void* d_out, int out_size, void* d_ws, size_t ws_size,
                              hipStream_t stream) {
  const float* y0     = (const float*)d_in[1];
  const int*   env    = (const int*)  d_in[2];
  const float* params = (const float*)d_in[3];
  float*       out    = (float*)d_out;
  int B = in_sizes[1] / 4096;

  init_tables<<<32, 256, 0, stream>>>();
  pde_main<<<B, 512, 0, stream>>>(y0, env, params, out);
}

// Round 11
// 41.523 us; speedup vs baseline: 2.1648x; 1.3207x over previous
//
#include <hip/hip_runtime.h>
#include <math.h>

#define P65 65
#define PLANE_U16 5248        // 5120 frag + 80 side + 48 pad (10496 B, 16B-multiple)
#define SIDE_OFF  5120
#define PSI_U16   8320        // 64*65 fp32 = 16640 B

// ---- device tables (built by init_tables each launch; deterministic) ----
// A-fragments for mfma_f32_16x16x32_bf16 (plain bf16). 18 blocks of 512:
//   blocks 0..9  : analysis table Gf (wrap-folded), tiles (mt0..4, kt0..1)
//   blocks 10..17: synthesis table Gt[j][k1]=G[k1][j], tiles (mt0..3, kt0..1)
//   within block: lane l, elem e -> Tbl[16*mt + (l&15)][32*kt + 8*(l>>4) + e]
__device__ __align__(16) ushort gAfrag[18*512];
__device__ float  g_MpN[65*65];   // NEGATED spectral multiplier (sign folded: we store x, not -x)
__device__ float  g64tab[64];     // G[64][j] = sin(2*pi*32*j/65)

__device__ __constant__ float c_DOMAIN[8] = {0.75f,1.0f,0.75f,1.0f,0.75f,1.0f,0.75f,1.0f};

__device__ inline ushort f2bf(float f) {          // RNE float -> bf16 bits
  unsigned u = __float_as_uint(f);
  return (ushort)((u + 0x7FFFu + ((u >> 16) & 1u)) >> 16);
}
__device__ inline float bf2f(ushort h) { return __uint_as_float(((unsigned)h) << 16); }

// G[r][i]: r<=32 -> cos(2*pi*r*i/65) ; r>=33 -> sin(2*pi*(r-32)*i/65)
__device__ inline double Gval(int r, int i) {
  int m = (r <= 32) ? r : (r - 32);
  int prod = (m * (i % 65)) % 65;
  double ang = 6.283185307179586476925286766559 * (double)prod / 65.0;
  return (r <= 32) ? cos(ang) : sin(ang);
}
__device__ inline double Gfold(int r, int i) {    // wrap-fold: += G[r][64] at i==0
  double v = Gval(r, i);
  if (i == 0) v += Gval(r, 64);
  return v;
}

__global__ void init_tables() {
  int tid = blockIdx.x*blockDim.x + threadIdx.x;
  int nth = gridDim.x*blockDim.x;
  for (int idx = tid; idx < 18*512; idx += nth) {
    int blk = idx >> 9, rem = idx & 511;
    int lane = rem >> 3, e = rem & 7;
    int i16 = lane & 15, kg = lane >> 4;
    float v = 0.f;
    if (blk < 10) {
      int mt = blk >> 1, kt = blk & 1;
      int r = 16*mt + i16;            // freq row (<65)
      int i = 32*kt + 8*kg + e;       // spatial col (<64)
      if (r < 65 && i < 64) v = (float)Gfold(r, i);
    } else {
      int b2 = blk - 10;
      int mt = b2 >> 1, kt = b2 & 1;
      int j  = 16*mt + i16;           // spatial row (<64)
      int k1 = 32*kt + 8*kg + e;      // freq col (<64; k=64 via rank-1)
      if (j < 64 && k1 < 64) v = (float)Gval(k1, j);
    }
    gAfrag[idx] = f2bf(v);
  }
  for (int idx = tid; idx < 65*65; idx += nth) {
    int k1 = idx/65, k2 = idx%65;
    float v = 0.f;
    if (k1 | k2) {
      double n1 = (k1==0)?(1.0/65.0):(2.0/65.0);
      double n2 = (k2==0)?(1.0/65.0):(2.0/65.0);
      int m1 = (k1<=32)?k1:(k1-32), m2 = (k2<=32)?k2:(k2-32);
      double b1 = 6.283185307179586476925286766559*(double)m1/65.0;
      double b2 = 6.283185307179586476925286766559*(double)m2/65.0;
      v = (float)((n1*n2)/(b1*b1 + b2*b2));     // NEGATED vs true Mp
    }
    g_MpN[idx] = v;
  }
  for (int idx = tid; idx < 64; idx += nth)
    g64tab[idx] = (float)Gval(64, idx);
}

typedef __attribute__((ext_vector_type(8))) short bf16x8;
typedef __attribute__((ext_vector_type(4))) float f32x4;

// One transform stage as MFMA tiles, plain bf16 operands, fragment-layout LDS planes.
// O[m][n] = sum_k Tbl[m][k] * Lin[n][k]  + optional rank-1 (k=64 sidecar).
// Frag layout: element (row n', col k') at blk=(n'>>4)*2+(k'>>5), lane=16*((k'>>3)&3)+(n'&15), e=k'&7.
// B-read for tile (nt,kt) = Lin + (nt*2+kt)*512 + lane*8 -> lane-contiguous, conflict-free.
template<int MT, int NT, int MR, int NR, int TBLOFF, bool SCALE, bool RK, bool PSI>
__device__ inline void stage(const ushort* __restrict__ Lin,
                             ushort* __restrict__ Lout,
                             float* __restrict__ psiout,
                             int wvu, int lane)
{
  const int lg = lane >> 4, li = lane & 15;
  for (int tile = wvu; tile < MT*NT; tile += 8) {
    int mt = tile / NT, nt = tile - mt*NT;
    int n = 16*nt + li;
    f32x4 acc = {0.f, 0.f, 0.f, 0.f};
    #pragma unroll
    for (int kt = 0; kt < 2; ++kt) {
      bf16x8 af = *(const bf16x8*)(gAfrag + (TBLOFF + mt*2 + kt)*512 + lane*8);
      bf16x8 bfr = *(const bf16x8*)(Lin + (nt*2 + kt)*512 + lane*8);
      acc = __builtin_amdgcn_mfma_f32_16x16x32_bf16(af, bfr, acc, 0, 0, 0);
    }
    float rkB = 0.f;
    if (RK) rkB = bf2f(Lin[SIDE_OFF + n]);
    int mbase = 16*mt + 4*lg;
    int wbase = (mt*2 + (nt>>1))*512 + ((2*nt + (li>>3))&3)*128 + (li&7);
    #pragma unroll
    for (int r = 0; r < 4; ++r) {
      int m = mbase + r;
      if (m < MR && n < NR) {
        float v = acc[r];
        if (SCALE) v *= g_MpN[m*65 + n];
        if (RK)    v = fmaf(g64tab[m], rkB, v);
        if (PSI) {
          psiout[n*P65 + m] = v;               // transposed: Ppsi[j1][j2]
        } else if (NT == 5 && nt == 4) {       // n==64 (only li==0 passes n<NR)
          Lout[SIDE_OFF + m] = f2bf(v);
        } else {
          Lout[wbase + (4*lg + r)*8] = f2bf(v);
        }
      }
    }
  }
}

__device__ inline float shflx(float v, int srclane) { return __shfl(v, srclane, 64); }

__global__ void __launch_bounds__(512) pde_main(const float* __restrict__ y0,
                                                const int*   __restrict__ env,
                                                const float* __restrict__ params,
                                                float*       __restrict__ out)
{
  // [PB (5248) | PA-region (8320)]. Chain: L->PA, S1 PA->PB, S2 PB->PA, S3 PA->PB,
  // S4 PB->psi where psi (fp32, 16640 B) overlays the dead PA region.
  __shared__ __align__(16) ushort Lsh[PLANE_U16 + PSI_U16];
  ushort* PB   = Lsh;
  ushort* PA   = Lsh + PLANE_U16;
  float*  Ppsi = (float*)(Lsh + PLANE_U16);

  const int b    = blockIdx.x;
  const int t    = threadIdx.x;
  const int lane = t & 63;
  const int wvu  = __builtin_amdgcn_readfirstlane(t >> 6);

  const int   e       = env[b];
  const float mu      = params[2*e];
  const float fdx     = c_DOMAIN[e] * (float)(3.14159265358979323846/64.0);
  const float inv_dx2 = 1.0f/(fdx*fdx);

  const float* xb = y0 + (size_t)b*4096;

  // ---- Phase L: wave owns rows 8wvu..8wvu+7, col=lane. Store x (sign folded into MpN)
  //      transposed into frag layout: one ds_write_b128 per thread.
  float xr[8];
  bf16x8 hv;
  #pragma unroll
  for (int k=0;k<8;++k) {
    float v = xb[(8*wvu + k)*64 + lane];
    xr[k] = v;
    hv[k] = (short)f2bf(v);
  }
  {
    int wb = ((lane>>4)*2 + (wvu>>2))*512 + ((wvu&3)*16 + (lane&15))*8;
    *(bf16x8*)(PA + wb) = hv;
  }
  __syncthreads();

  // ---- S1: A1[k1][c2] = sum_j Gf[k1][j]*x[j][c2]              (M=65,N=64,K=64 folded)
  stage<5,4,65,64, 0,false,false,false>(PA, PB, nullptr, wvu, lane);
  __syncthreads();
  // ---- S2: spec[k2][k1] = MpN .* sum_c2 Gf[k2][c2]*A1[k1][c2] (M=65,N=65; sidecar k1=64)
  stage<5,5,65,65, 0,true ,false,false>(PB, PA, nullptr, wvu, lane);
  __syncthreads();
  // ---- S3: V[j1][k2] = sum_k1 G[k1][j1]*spec[k1][k2]           (M=64,N=65; rank-1 k1=64)
  stage<4,5,64,65,10,false,true ,false>(PA, PB, nullptr, wvu, lane);
  __syncthreads();
  // ---- S4: psi[j1][j2] = sum_k2 G[k2][j2]*V[j1][k2]            (M=64,N=64; rank-1 k2=64)
  stage<4,4,64,64,10,false,true ,true >(PB, nullptr, Ppsi, wvu, lane);
  __syncthreads();

  // ---- stencil: psi from LDS fp32; own x rows from regs, 2 boundary rows from global (L2-hot)
  {
    const int c = lane, cm = (c+63)&63, cp = (c+1)&63;
    const int j0 = wvu*8, jm0 = (j0+63)&63, jp8 = (j0+8)&63;
    float xbm = xb[jm0*64 + c];
    float xbp = xb[jp8*64 + c];
    float* op = out + (size_t)b*4096;

    float xm_c = xbm,   xm_m = shflx(xm_c, cm), xm_p = shflx(xm_c, cp);
    float xc_c = xr[0], xc_m = shflx(xc_c, cm), xc_p = shflx(xc_c, cp);
    float pm_m = Ppsi[jm0*P65+cm], pm_c = Ppsi[jm0*P65+c], pm_p = Ppsi[jm0*P65+cp];
    float pc_m = Ppsi[j0 *P65+cm], pc_c = Ppsi[j0 *P65+c], pc_p = Ppsi[j0 *P65+cp];

    #pragma unroll
    for (int m=0;m<8;++m) {
      int j = j0 + m, jp = (j+1)&63;
      float xn_c = (m < 7) ? xr[m+1] : xbp;
      float xn_m = shflx(xn_c, cm), xn_p = shflx(xn_c, cp);
      float pn_m = Ppsi[jp*P65+cm], pn_c = Ppsi[jp*P65+c], pn_p = Ppsi[jp*P65+cp];

      float J1 = (pn_c - pm_c)*(xc_p - xc_m) - (pc_p - pc_m)*(xn_c - xm_c);
      float J2 = xc_p*(pn_p - pm_p) - xc_m*(pn_m - pm_m)
               - xn_c*(pn_p - pn_m) + xm_c*(pm_p - pm_m);
      float J3 = xn_p*(pn_c - pc_p) - xm_m*(pc_m - pm_c)
               - xn_m*(pn_c - pc_m) + xm_p*(pc_p - pm_c);
      float lap = (xm_c + xn_c + xc_m + xc_p + xn_m - 4.0f*xc_c) * inv_dx2;

      op[j*64 + c] = -(J1 + J2 + J3)*(0.25f/3.0f) + mu*lap;

      xm_m=xc_m; xm_c=xc_c; xm_p=xc_p;  pm_m=pc_m; pm_c=pc_c; pm_p=pc_p;
      xc_m=xn_m; xc_c=xn_c; xc_p=xn_p;  pc_m=pn_m; pc_c=pn_c; pc_p=pn_p;
    }
  }
}

extern "C" void kernel_launch(void* const* d_in, const int* in_sizes, int n_in,
                              void* d_out, int out_size, void* d_ws, size_t ws_size,
                              hipStream_t stream) {
  const float* y0     = (const float*)d_in[1];
  const int*   env    = (const int*)  d_in[2];
  const float* params = (const float*)d_in[3];
  float*       out    = (float*)d_out;
  int B = in_sizes[1] / 4096;

  init_tables<<<32, 256, 0, stream>>>();
  pde_main<<<B, 512, 0, stream>>>(y0, env, params, out);
}